// Round 3
// baseline (749.087 us; speedup 1.0000x reference)
//
#include <hip/hip_runtime.h>
#include <hip/hip_fp16.h>
#include <math.h>

#define DIM      32
#define HDIM     16                // DIM/2 float2 pairs per row
#define N_NODES  100000
#define N_EDGES  1600000
#define L0       0.1f

// ---- binning parameters ----
#define NB       256               // node buckets
#define NPB      391               // nodes per bucket (256*391 = 100,096)
#define CAP      14336             // records per bucket (exp 12,512, +16 sigma)
#define TILE     2048              // edges per bin tile -> 4096 records
#define NT       ((N_EDGES + TILE - 1) / TILE)   // 782 tiles

// ===========================================================================
// Measured model (R0/R2): scattered global atomics are BYTE-bound at ~1 TB/s
// (R0: 204.8MB->203us, R2: 307MB->296us).  This path replaces them entirely:
// phase 1 sorts 4B records (dest_local | nb<<9) into node buckets with
// LDS-staged coalesced writes; phase 2 accumulates each bucket's grad slice
// in LDS (f32 atomics, free at HBM level) and writes it once, recomputing f
// per half-edge (transcendentals are cheap; bytes are not).
// ===========================================================================

// ---- Phase 1: tile-local counting sort of edge records by node bucket ----
__global__ __launch_bounds__(256) void bin_kernel(
    const int*    __restrict__ edges,
    unsigned int* __restrict__ gcursor,   // NB counters (ws, zeroed)
    unsigned int* __restrict__ recs_g)    // NB*CAP u32 records (ws)
{
    __shared__ unsigned int  recs[2 * TILE];   // 16 KB
    __shared__ unsigned int  srec[2 * TILE];   // 16 KB sorted
    __shared__ unsigned char rb  [2 * TILE];   // 4 KB bucket per record
    __shared__ unsigned char srb [2 * TILE];   // 4 KB bucket per sorted slot
    __shared__ unsigned int  hist [NB];
    __shared__ unsigned int  lscan[NB];
    __shared__ unsigned int  gbase[NB];
    __shared__ unsigned int  cnt  [NB];

    const int t    = threadIdx.x;
    const int base = blockIdx.x * TILE;
    const int nedge = min(TILE, N_EDGES - base);
    const int nrec  = 2 * nedge;

    hist[t] = 0;
    cnt[t]  = 0;
    __syncthreads();

    // build records (compact: record index order == edge index order)
    #pragma unroll
    for (int i = 0; i < TILE / 256; ++i) {
        const int e = base + i * 256 + t;
        if (e < N_EDGES) {
            const int2 ev = ((const int2*)edges)[e];
            const int bu = ev.x / NPB;
            const int du = ev.x - bu * NPB;
            const int bv = ev.y / NPB;
            const int dv = ev.y - bv * NPB;
            const int r0 = (i * 256 + t) * 2;
            recs[r0]     = (unsigned)du | ((unsigned)ev.y << 9);
            rb[r0]       = (unsigned char)bu;
            recs[r0 + 1] = (unsigned)dv | ((unsigned)ev.x << 9);
            rb[r0 + 1]   = (unsigned char)bv;
            atomicAdd(&hist[bu], 1u);
            atomicAdd(&hist[bv], 1u);
        }
    }
    __syncthreads();

    // inclusive scan of hist into lscan (Hillis-Steele over 256 entries)
    lscan[t] = hist[t];
    __syncthreads();
    for (int off = 1; off < NB; off <<= 1) {
        const unsigned add = (t >= off) ? lscan[t - off] : 0u;
        __syncthreads();
        lscan[t] += add;
        __syncthreads();
    }
    // claim global bases; convert lscan to exclusive
    const unsigned myCnt = hist[t];
    gbase[t] = myCnt ? atomicAdd(&gcursor[t], myCnt) : 0u;
    const unsigned excl = lscan[t] - myCnt;
    __syncthreads();
    lscan[t] = excl;
    __syncthreads();

    // scatter into sorted LDS order
    for (int r = t; r < nrec; r += 256) {
        const unsigned char b  = rb[r];
        const unsigned int  lo = atomicAdd(&cnt[b], 1u);
        const unsigned int  pos = lscan[b] + lo;
        srec[pos] = recs[r];
        srb[pos]  = b;
    }
    __syncthreads();

    // coalesced write-out of per-bucket runs
    for (int j = t; j < nrec; j += 256) {
        const unsigned char b   = srb[j];
        const unsigned int  idx = gbase[b] + ((unsigned)j - lscan[b]);
        if (idx < CAP)                         // defensive (16-sigma margin)
            recs_g[(unsigned)b * CAP + idx] = srec[j];
    }
}

// ---- Phase 2: per-bucket LDS-resident gather/accumulate ----
__global__ __launch_bounds__(1024) void gather_kernel(
    const float*        __restrict__ x,
    const unsigned int* __restrict__ recs_g,
    const unsigned int* __restrict__ gcursor,
    float*              __restrict__ out)     // out[0] energy (pre-zeroed)
{
    __shared__ float  lg[NPB * DIM];          // 50,048 B grad slice
    __shared__ double s_e[16];

    const int b     = blockIdx.x;
    const int t     = threadIdx.x;
    const int lane  = t & 63;
    const int k     = lane & 15;              // float2 pair index
    const int qId   = (t >> 6) * 4 + (lane >> 4);   // 0..63 records in flight
    const int node0 = b * NPB;
    const int nnode = min(NPB, N_NODES - node0);

    for (int j = t; j < NPB * DIM; j += 1024) lg[j] = 0.0f;
    __syncthreads();

    const int nrec = min((int)gcursor[b], CAP);
    const float2* __restrict__ x2 = (const float2*)x;
    const float Jx = (k == 0) ? -1.0f : 1.0f;

    double energy = 0.0;

    for (int i = qId; i < nrec; i += 64) {
        const unsigned int rec = recs_g[b * CAP + i];
        const int dl = (int)(rec & 511u);
        const int nb = (int)(rec >> 9);

        const float2 xn = x2[nb * HDIM + k];              // cold gather
        const float2 xd = x2[(node0 + dl) * HDIM + k];    // hot (slice)

        // identical dot/reduce structure to the R0 kernel -> identical p for
        // both half-edges of an edge (products commute), identical f.
        float p = Jx * xd.x * xn.x + xd.y * xn.y;
        #pragma unroll
        for (int off = 8; off; off >>= 1)
            p += __shfl_xor(p, off, 16);

        const float inner = fminf(p, -1.0000001f);
        const float zm1   = -inner - 1.0f;
        const float s     = sqrtf(zm1 * (zm1 + 2.0f));
        const float dist  = log1pf(zm1 + s);
        const float delta = dist - L0;
        const float f     = -delta / (s + 1e-9f);

        atomicAdd(&lg[dl * DIM + 2 * k],     f * Jx * xn.x);
        atomicAdd(&lg[dl * DIM + 2 * k + 1], f * xn.y);
        if (k == 0)                                   // 2 records per edge
            energy += 0.25 * (double)delta * (double)delta;
    }

    // energy: butterfly within wave, then block reduce, one atomic per block
    #pragma unroll
    for (int off = 32; off; off >>= 1)
        energy += __shfl_xor(energy, off, 64);
    if (lane == 0) s_e[t >> 6] = energy;
    __syncthreads();                // also orders LDS atomics before writeout
    if (t == 0) {
        double tot = 0.0;
        #pragma unroll
        for (int w = 0; w < 16; ++w) tot += s_e[w];
        atomicAdd(&out[0], (float)tot);
    }

    // coalesced slice writeout (covers every grad element across blocks)
    float* __restrict__ grad = out + 1;
    const int lim = nnode * DIM;
    for (int j = t; j < lim; j += 1024)
        grad[node0 * DIM + j] = lg[j];
}

// ===========================================================================
// Fallback 1 (ws >= 6.4MB): round-0 f16-packed-atomic kernel, 266 us.
// ===========================================================================
__global__ __launch_bounds__(256) void spring_edge_f16_kernel(
    const float*  __restrict__ x,
    const int*    __restrict__ edges,
    __half2*      __restrict__ grad_h,
    float*        __restrict__ energy_ws)
{
    const int tid   = threadIdx.x;
    const int lane  = tid & 63;
    const int k     = lane & 15;
    const int quad  = lane >> 4;
    const int qId   = ((blockIdx.x * blockDim.x + tid) >> 6) * 4 + quad;
    const int nQuad = ((gridDim.x * blockDim.x) >> 6) * 4;

    const float2* __restrict__ x2 = (const float2*)x;
    const float Jx = (k == 0) ? -1.0f : 1.0f;

    double energy = 0.0;

    for (int e0 = qId; e0 < N_EDGES; e0 += 2 * nQuad) {
        const int  e1 = e0 + nQuad;
        const bool a1 = (e1 < N_EDGES);

        const int2 ev0 = ((const int2*)edges)[e0];
        const int2 ev1 = a1 ? ((const int2*)edges)[e1] : make_int2(0, 0);
        const float2 xu0 = x2[ev0.x * HDIM + k];
        const float2 xv0 = x2[ev0.y * HDIM + k];
        const float2 xu1 = x2[ev1.x * HDIM + k];
        const float2 xv1 = x2[ev1.y * HDIM + k];

        float p0 = Jx * xu0.x * xv0.x + xu0.y * xv0.y;
        float p1 = Jx * xu1.x * xv1.x + xu1.y * xv1.y;
        #pragma unroll
        for (int off = 8; off; off >>= 1) {
            p0 += __shfl_xor(p0, off, 16);
            p1 += __shfl_xor(p1, off, 16);
        }

        {
            const float inner = fminf(p0, -1.0000001f);
            const float zm1   = -inner - 1.0f;
            const float s     = sqrtf(zm1 * (zm1 + 2.0f));
            const float dist  = log1pf(zm1 + s);
            const float delta = dist - L0;
            const float f     = -delta / (s + 1e-9f);
            unsafeAtomicAdd(&grad_h[ev0.x * HDIM + k],
                            __floats2half2_rn(f * Jx * xv0.x, f * xv0.y));
            unsafeAtomicAdd(&grad_h[ev0.y * HDIM + k],
                            __floats2half2_rn(f * Jx * xu0.x, f * xu0.y));
            if (k == 0) energy += 0.5 * (double)delta * (double)delta;
        }
        if (a1) {
            const float inner = fminf(p1, -1.0000001f);
            const float zm1   = -inner - 1.0f;
            const float s     = sqrtf(zm1 * (zm1 + 2.0f));
            const float dist  = log1pf(zm1 + s);
            const float delta = dist - L0;
            const float f     = -delta / (s + 1e-9f);
            unsafeAtomicAdd(&grad_h[ev1.x * HDIM + k],
                            __floats2half2_rn(f * Jx * xv1.x, f * xv1.y));
            unsafeAtomicAdd(&grad_h[ev1.y * HDIM + k],
                            __floats2half2_rn(f * Jx * xu1.x, f * xu1.y));
            if (k == 0) energy += 0.5 * (double)delta * (double)delta;
        }
    }

    #pragma unroll
    for (int off = 32; off; off >>= 1)
        energy += __shfl_xor(energy, off, 64);

    __shared__ double s_e[4];
    if (lane == 0) s_e[tid >> 6] = energy;
    __syncthreads();
    if (tid == 0)
        atomicAdd(energy_ws, (float)(s_e[0] + s_e[1] + s_e[2] + s_e[3]));
}

__global__ __launch_bounds__(256) void convert_kernel(
    const __half2* __restrict__ grad_h,
    const float*   __restrict__ energy_ws,
    float*         __restrict__ out)
{
    const int i = blockIdx.x * 256 + threadIdx.x;
    if (i < N_NODES * HDIM) {
        const float2 f = __half22float2(grad_h[i]);
        out[1 + 2 * i]     = f.x;
        out[1 + 2 * i + 1] = f.y;
    }
    if (i == 0) out[0] = *energy_ws;
}

// ===========================================================================
// Fallback 2 (no usable ws): known-correct fused kernel.
// ===========================================================================
__global__ __launch_bounds__(256) void spring_edge_kernel(
    const float* __restrict__ x,
    const int*   __restrict__ edges,
    float*       __restrict__ out)
{
    const int tid    = threadIdx.x;
    const int lane   = tid & 63;
    const int d      = lane & 31;
    const int half   = lane >> 5;
    const int waveId = (blockIdx.x * blockDim.x + tid) >> 6;
    const int nWaves = (gridDim.x * blockDim.x) >> 6;

    float* __restrict__ grad = out + 1;
    const float Jd = (d == 0) ? -1.0f : 1.0f;
    double energy = 0.0;

    for (int e0 = waveId * 2; e0 < N_EDGES; e0 += nWaves * 2) {
        const int  e      = e0 + half;
        const bool active = (e < N_EDGES);
        int u = 0, v = 0;
        float xu = 0.0f, xv = 0.0f;
        if (active) {
            u  = edges[2 * e];
            v  = edges[2 * e + 1];
            xu = x[u * DIM + d];
            xv = x[v * DIM + d];
        }
        float p = xu * xv;
        if (d == 0) p = -p;
        #pragma unroll
        for (int off = 16; off; off >>= 1)
            p += __shfl_xor(p, off, 32);

        const float inner  = fminf(p, -1.0000001f);
        const float zm1    = -inner - 1.0f;
        const float s      = sqrtf(zm1 * (zm1 + 2.0f));
        const float dist   = log1pf(zm1 + s);
        const float delta  = dist - L0;
        const float factor = -delta / (s + 1e-9f);

        if (active) {
            atomicAdd(&grad[u * DIM + d], factor * xv * Jd);
            atomicAdd(&grad[v * DIM + d], factor * xu * Jd);
            if (d == 0)
                energy += 0.5 * (double)delta * (double)delta;
        }
    }
    #pragma unroll
    for (int off = 32; off; off >>= 1)
        energy += __shfl_xor(energy, off, 64);
    __shared__ double s_e[4];
    if (lane == 0) s_e[tid >> 6] = energy;
    __syncthreads();
    if (tid == 0)
        atomicAdd(&out[0], (float)(s_e[0] + s_e[1] + s_e[2] + s_e[3]));
}

extern "C" void kernel_launch(void* const* d_in, const int* in_sizes, int n_in,
                              void* d_out, int out_size, void* d_ws, size_t ws_size,
                              hipStream_t stream) {
    const float* x     = (const float*)d_in[0];
    const int*   edges = (const int*)d_in[1];
    float*       out   = (float*)d_out;

    // ---- binning workspace layout ----
    const size_t cur_bytes = (size_t)NB * sizeof(unsigned int);       // 1 KB
    const size_t rec_off   = 1024;                                    // aligned
    const size_t rec_bytes = (size_t)NB * CAP * sizeof(unsigned int); // 14.68 MB
    const size_t bin_need  = rec_off + rec_bytes;

    const size_t grad_bytes = (size_t)N_NODES * HDIM * sizeof(__half2); // 6.4 MB
    const size_t f16_need   = grad_bytes + sizeof(float);

    if (ws_size >= bin_need) {
        unsigned int* gcursor = (unsigned int*)d_ws;
        unsigned int* recs_g  = (unsigned int*)((char*)d_ws + rec_off);

        hipMemsetAsync(gcursor, 0, cur_bytes, stream);
        hipMemsetAsync(out, 0, sizeof(float), stream);    // energy slot
        bin_kernel<<<NT, 256, 0, stream>>>(edges, gcursor, recs_g);
        gather_kernel<<<NB, 1024, 0, stream>>>(x, recs_g, gcursor, out);
    } else if (ws_size >= f16_need) {
        __half2* grad_h    = (__half2*)d_ws;
        float*   energy_ws = (float*)((char*)d_ws + grad_bytes);

        hipMemsetAsync(d_ws, 0, f16_need, stream);
        spring_edge_f16_kernel<<<4096, 256, 0, stream>>>(x, edges, grad_h,
                                                         energy_ws);
        convert_kernel<<<(N_NODES * HDIM + 255) / 256, 256, 0, stream>>>(
            grad_h, energy_ws, out);
    } else {
        hipMemsetAsync(out, 0, (size_t)out_size * sizeof(float), stream);
        spring_edge_kernel<<<4096, 256, 0, stream>>>(x, edges, out);
    }
}

// Round 4
// 687.700 us; speedup vs baseline: 1.0893x; 1.0893x over previous
//
#include <hip/hip_runtime.h>
#include <hip/hip_fp16.h>
#include <math.h>

#define DIM      32
#define HDIM     16                // DIM/2 float2 pairs per row
#define N_NODES  100000
#define N_EDGES  1600000
#define L0       0.1f

// ---- binning parameters ----
#define NB       256               // node buckets
#define NPB      391               // nodes per bucket (256*391 = 100,096)
#define CAP      14336             // records per bucket (exp 12,512, +16 sigma)
#define TILE     2048              // edges per bin tile -> 4096 records
#define NT       ((N_EDGES + TILE - 1) / TILE)   // 782 tiles
#define GPB      2                 // gather blocks per bucket
#define CHUNK    2048              // records staged to LDS per pass

// ===========================================================================
// R3 post-mortem: gather was latency-starved (287 GB/s, 47% occ, 1 blk/CU,
// one dependent rec->xn chain per quad).  R4 keeps bin_kernel identical and
// rebuilds gather for concurrency: 2 blocks/bucket (2 blk/CU, ~94% occ),
// records staged to LDS in coalesced chunks, and a 2-deep unrolled quad loop
// so each quad keeps 2 independent row-gathers in flight (256/CU total).
// Slices merge via coalesced global f32 atomics (dense, line-packed — not
// the scattered-line atomics that bounded R0 at 1 TB/s).
// ===========================================================================

// ---- Phase 1: tile-local counting sort of edge records by node bucket ----
__global__ __launch_bounds__(256) void bin_kernel(
    const int*    __restrict__ edges,
    unsigned int* __restrict__ gcursor,   // NB counters (ws, zeroed)
    unsigned int* __restrict__ recs_g)    // NB*CAP u32 records (ws)
{
    __shared__ unsigned int  recs[2 * TILE];   // 16 KB
    __shared__ unsigned int  srec[2 * TILE];   // 16 KB sorted
    __shared__ unsigned char rb  [2 * TILE];   // 4 KB bucket per record
    __shared__ unsigned char srb [2 * TILE];   // 4 KB bucket per sorted slot
    __shared__ unsigned int  hist [NB];
    __shared__ unsigned int  lscan[NB];
    __shared__ unsigned int  gbase[NB];
    __shared__ unsigned int  cnt  [NB];

    const int t    = threadIdx.x;
    const int base = blockIdx.x * TILE;
    const int nedge = min(TILE, N_EDGES - base);
    const int nrec  = 2 * nedge;

    hist[t] = 0;
    cnt[t]  = 0;
    __syncthreads();

    // build records (compact: record index order == edge index order)
    #pragma unroll
    for (int i = 0; i < TILE / 256; ++i) {
        const int e = base + i * 256 + t;
        if (e < N_EDGES) {
            const int2 ev = ((const int2*)edges)[e];
            const int bu = ev.x / NPB;
            const int du = ev.x - bu * NPB;
            const int bv = ev.y / NPB;
            const int dv = ev.y - bv * NPB;
            const int r0 = (i * 256 + t) * 2;
            recs[r0]     = (unsigned)du | ((unsigned)ev.y << 9);
            rb[r0]       = (unsigned char)bu;
            recs[r0 + 1] = (unsigned)dv | ((unsigned)ev.x << 9);
            rb[r0 + 1]   = (unsigned char)bv;
            atomicAdd(&hist[bu], 1u);
            atomicAdd(&hist[bv], 1u);
        }
    }
    __syncthreads();

    // inclusive scan of hist into lscan (Hillis-Steele over 256 entries)
    lscan[t] = hist[t];
    __syncthreads();
    for (int off = 1; off < NB; off <<= 1) {
        const unsigned add = (t >= off) ? lscan[t - off] : 0u;
        __syncthreads();
        lscan[t] += add;
        __syncthreads();
    }
    // claim global bases; convert lscan to exclusive
    const unsigned myCnt = hist[t];
    gbase[t] = myCnt ? atomicAdd(&gcursor[t], myCnt) : 0u;
    const unsigned excl = lscan[t] - myCnt;
    __syncthreads();
    lscan[t] = excl;
    __syncthreads();

    // scatter into sorted LDS order
    for (int r = t; r < nrec; r += 256) {
        const unsigned char b  = rb[r];
        const unsigned int  lo = atomicAdd(&cnt[b], 1u);
        const unsigned int  pos = lscan[b] + lo;
        srec[pos] = recs[r];
        srb[pos]  = b;
    }
    __syncthreads();

    // coalesced write-out of per-bucket runs
    for (int j = t; j < nrec; j += 256) {
        const unsigned char b   = srb[j];
        const unsigned int  idx = gbase[b] + ((unsigned)j - lscan[b]);
        if (idx < CAP)                         // defensive (16-sigma margin)
            recs_g[(unsigned)b * CAP + idx] = srec[j];
    }
}

// ---- Phase 2: per-bucket LDS-resident gather/accumulate (2 blocks/bucket) --
__global__ __launch_bounds__(1024) void gather_kernel(
    const float*        __restrict__ x,
    const unsigned int* __restrict__ recs_g,
    const unsigned int* __restrict__ gcursor,
    float*              __restrict__ out)     // pre-zeroed (energy + grad)
{
    __shared__ float        lg[NPB * DIM];    // 50,048 B grad slice
    __shared__ unsigned int rbuf[CHUNK];      // 8 KB staged records
    __shared__ double       s_e[16];

    const int b     = blockIdx.x >> 1;        // bucket
    const int sub   = blockIdx.x & 1;         // which half of the records
    const int t     = threadIdx.x;
    const int lane  = t & 63;
    const int k     = lane & 15;              // float2 pair index
    const int qId   = (t >> 6) * 4 + (lane >> 4);   // quad id 0..63
    const int node0 = b * NPB;
    const int nnode = min(NPB, N_NODES - node0);

    for (int j = t; j < NPB * DIM; j += 1024) lg[j] = 0.0f;

    const int nrec  = min((int)gcursor[b], CAP);
    const int half  = (nrec + 1) >> 1;
    const int start = sub ? half : 0;
    const int end   = sub ? nrec : half;

    const float2* __restrict__ x2 = (const float2*)x;
    const float Jx = (k == 0) ? -1.0f : 1.0f;

    double energy = 0.0;
    __syncthreads();                          // lg zeroed before use

    for (int c = start; c < end; c += CHUNK) {
        const int n = min(CHUNK, end - c);
        // coalesced stage of this chunk's records
        for (int j = t; j < n; j += 1024)
            rbuf[j] = recs_g[b * CAP + c + j];
        __syncthreads();

        int i = qId;
        // 2-deep unroll: two independent row gathers in flight per quad
        for (; i + 64 < n; i += 128) {
            const unsigned int rec0 = rbuf[i];
            const unsigned int rec1 = rbuf[i + 64];
            const int dl0 = (int)(rec0 & 511u), nb0 = (int)(rec0 >> 9);
            const int dl1 = (int)(rec1 & 511u), nb1 = (int)(rec1 >> 9);

            const float2 xn0 = x2[nb0 * HDIM + k];
            const float2 xd0 = x2[(node0 + dl0) * HDIM + k];
            const float2 xn1 = x2[nb1 * HDIM + k];
            const float2 xd1 = x2[(node0 + dl1) * HDIM + k];

            float p0 = Jx * xd0.x * xn0.x + xd0.y * xn0.y;
            float p1 = Jx * xd1.x * xn1.x + xd1.y * xn1.y;
            #pragma unroll
            for (int off = 8; off; off >>= 1) {
                p0 += __shfl_xor(p0, off, 16);
                p1 += __shfl_xor(p1, off, 16);
            }
            {
                const float inner = fminf(p0, -1.0000001f);
                const float zm1   = -inner - 1.0f;
                const float s     = sqrtf(zm1 * (zm1 + 2.0f));
                const float dist  = log1pf(zm1 + s);
                const float delta = dist - L0;
                const float f     = -delta / (s + 1e-9f);
                atomicAdd(&lg[dl0 * DIM + 2 * k],     f * Jx * xn0.x);
                atomicAdd(&lg[dl0 * DIM + 2 * k + 1], f * xn0.y);
                if (k == 0) energy += 0.25 * (double)delta * (double)delta;
            }
            {
                const float inner = fminf(p1, -1.0000001f);
                const float zm1   = -inner - 1.0f;
                const float s     = sqrtf(zm1 * (zm1 + 2.0f));
                const float dist  = log1pf(zm1 + s);
                const float delta = dist - L0;
                const float f     = -delta / (s + 1e-9f);
                atomicAdd(&lg[dl1 * DIM + 2 * k],     f * Jx * xn1.x);
                atomicAdd(&lg[dl1 * DIM + 2 * k + 1], f * xn1.y);
                if (k == 0) energy += 0.25 * (double)delta * (double)delta;
            }
        }
        if (i < n) {                           // tail record
            const unsigned int rec = rbuf[i];
            const int dl = (int)(rec & 511u), nb = (int)(rec >> 9);
            const float2 xn = x2[nb * HDIM + k];
            const float2 xd = x2[(node0 + dl) * HDIM + k];
            float p = Jx * xd.x * xn.x + xd.y * xn.y;
            #pragma unroll
            for (int off = 8; off; off >>= 1)
                p += __shfl_xor(p, off, 16);
            const float inner = fminf(p, -1.0000001f);
            const float zm1   = -inner - 1.0f;
            const float s     = sqrtf(zm1 * (zm1 + 2.0f));
            const float dist  = log1pf(zm1 + s);
            const float delta = dist - L0;
            const float f     = -delta / (s + 1e-9f);
            atomicAdd(&lg[dl * DIM + 2 * k],     f * Jx * xn.x);
            atomicAdd(&lg[dl * DIM + 2 * k + 1], f * xn.y);
            if (k == 0) energy += 0.25 * (double)delta * (double)delta;
        }
        __syncthreads();                       // rbuf reuse barrier
    }

    // energy: butterfly within wave, block reduce, one atomic per block
    #pragma unroll
    for (int off = 32; off; off >>= 1)
        energy += __shfl_xor(energy, off, 64);
    if (lane == 0) s_e[t >> 6] = energy;
    __syncthreads();                // also orders LDS atomics before writeout
    if (t == 0) {
        double tot = 0.0;
        #pragma unroll
        for (int w = 0; w < 16; ++w) tot += s_e[w];
        atomicAdd(&out[0], (float)tot);
    }

    // coalesced slice merge (grad pre-zeroed; dense line-packed atomics)
    float* __restrict__ grad = out + 1;
    const int lim = nnode * DIM;
    for (int j = t; j < lim; j += 1024)
        atomicAdd(&grad[node0 * DIM + j], lg[j]);
}

// ===========================================================================
// Fallback 1 (ws >= 6.4MB): round-0 f16-packed-atomic kernel, 266 us.
// ===========================================================================
__global__ __launch_bounds__(256) void spring_edge_f16_kernel(
    const float*  __restrict__ x,
    const int*    __restrict__ edges,
    __half2*      __restrict__ grad_h,
    float*        __restrict__ energy_ws)
{
    const int tid   = threadIdx.x;
    const int lane  = tid & 63;
    const int k     = lane & 15;
    const int quad  = lane >> 4;
    const int qId   = ((blockIdx.x * blockDim.x + tid) >> 6) * 4 + quad;
    const int nQuad = ((gridDim.x * blockDim.x) >> 6) * 4;

    const float2* __restrict__ x2 = (const float2*)x;
    const float Jx = (k == 0) ? -1.0f : 1.0f;

    double energy = 0.0;

    for (int e0 = qId; e0 < N_EDGES; e0 += 2 * nQuad) {
        const int  e1 = e0 + nQuad;
        const bool a1 = (e1 < N_EDGES);

        const int2 ev0 = ((const int2*)edges)[e0];
        const int2 ev1 = a1 ? ((const int2*)edges)[e1] : make_int2(0, 0);
        const float2 xu0 = x2[ev0.x * HDIM + k];
        const float2 xv0 = x2[ev0.y * HDIM + k];
        const float2 xu1 = x2[ev1.x * HDIM + k];
        const float2 xv1 = x2[ev1.y * HDIM + k];

        float p0 = Jx * xu0.x * xv0.x + xu0.y * xv0.y;
        float p1 = Jx * xu1.x * xv1.x + xu1.y * xv1.y;
        #pragma unroll
        for (int off = 8; off; off >>= 1) {
            p0 += __shfl_xor(p0, off, 16);
            p1 += __shfl_xor(p1, off, 16);
        }

        {
            const float inner = fminf(p0, -1.0000001f);
            const float zm1   = -inner - 1.0f;
            const float s     = sqrtf(zm1 * (zm1 + 2.0f));
            const float dist  = log1pf(zm1 + s);
            const float delta = dist - L0;
            const float f     = -delta / (s + 1e-9f);
            unsafeAtomicAdd(&grad_h[ev0.x * HDIM + k],
                            __floats2half2_rn(f * Jx * xv0.x, f * xv0.y));
            unsafeAtomicAdd(&grad_h[ev0.y * HDIM + k],
                            __floats2half2_rn(f * Jx * xu0.x, f * xu0.y));
            if (k == 0) energy += 0.5 * (double)delta * (double)delta;
        }
        if (a1) {
            const float inner = fminf(p1, -1.0000001f);
            const float zm1   = -inner - 1.0f;
            const float s     = sqrtf(zm1 * (zm1 + 2.0f));
            const float dist  = log1pf(zm1 + s);
            const float delta = dist - L0;
            const float f     = -delta / (s + 1e-9f);
            unsafeAtomicAdd(&grad_h[ev1.x * HDIM + k],
                            __floats2half2_rn(f * Jx * xv1.x, f * xv1.y));
            unsafeAtomicAdd(&grad_h[ev1.y * HDIM + k],
                            __floats2half2_rn(f * Jx * xu1.x, f * xu1.y));
            if (k == 0) energy += 0.5 * (double)delta * (double)delta;
        }
    }

    #pragma unroll
    for (int off = 32; off; off >>= 1)
        energy += __shfl_xor(energy, off, 64);

    __shared__ double s_e[4];
    if (lane == 0) s_e[tid >> 6] = energy;
    __syncthreads();
    if (tid == 0)
        atomicAdd(energy_ws, (float)(s_e[0] + s_e[1] + s_e[2] + s_e[3]));
}

__global__ __launch_bounds__(256) void convert_kernel(
    const __half2* __restrict__ grad_h,
    const float*   __restrict__ energy_ws,
    float*         __restrict__ out)
{
    const int i = blockIdx.x * 256 + threadIdx.x;
    if (i < N_NODES * HDIM) {
        const float2 f = __half22float2(grad_h[i]);
        out[1 + 2 * i]     = f.x;
        out[1 + 2 * i + 1] = f.y;
    }
    if (i == 0) out[0] = *energy_ws;
}

// ===========================================================================
// Fallback 2 (no usable ws): known-correct fused kernel.
// ===========================================================================
__global__ __launch_bounds__(256) void spring_edge_kernel(
    const float* __restrict__ x,
    const int*   __restrict__ edges,
    float*       __restrict__ out)
{
    const int tid    = threadIdx.x;
    const int lane   = tid & 63;
    const int d      = lane & 31;
    const int half   = lane >> 5;
    const int waveId = (blockIdx.x * blockDim.x + tid) >> 6;
    const int nWaves = (gridDim.x * blockDim.x) >> 6;

    float* __restrict__ grad = out + 1;
    const float Jd = (d == 0) ? -1.0f : 1.0f;
    double energy = 0.0;

    for (int e0 = waveId * 2; e0 < N_EDGES; e0 += nWaves * 2) {
        const int  e      = e0 + half;
        const bool active = (e < N_EDGES);
        int u = 0, v = 0;
        float xu = 0.0f, xv = 0.0f;
        if (active) {
            u  = edges[2 * e];
            v  = edges[2 * e + 1];
            xu = x[u * DIM + d];
            xv = x[v * DIM + d];
        }
        float p = xu * xv;
        if (d == 0) p = -p;
        #pragma unroll
        for (int off = 16; off; off >>= 1)
            p += __shfl_xor(p, off, 32);

        const float inner  = fminf(p, -1.0000001f);
        const float zm1    = -inner - 1.0f;
        const float s      = sqrtf(zm1 * (zm1 + 2.0f));
        const float dist   = log1pf(zm1 + s);
        const float delta  = dist - L0;
        const float factor = -delta / (s + 1e-9f);

        if (active) {
            atomicAdd(&grad[u * DIM + d], factor * xv * Jd);
            atomicAdd(&grad[v * DIM + d], factor * xu * Jd);
            if (d == 0)
                energy += 0.5 * (double)delta * (double)delta;
        }
    }
    #pragma unroll
    for (int off = 32; off; off >>= 1)
        energy += __shfl_xor(energy, off, 64);
    __shared__ double s_e[4];
    if (lane == 0) s_e[tid >> 6] = energy;
    __syncthreads();
    if (tid == 0)
        atomicAdd(&out[0], (float)(s_e[0] + s_e[1] + s_e[2] + s_e[3]));
}

extern "C" void kernel_launch(void* const* d_in, const int* in_sizes, int n_in,
                              void* d_out, int out_size, void* d_ws, size_t ws_size,
                              hipStream_t stream) {
    const float* x     = (const float*)d_in[0];
    const int*   edges = (const int*)d_in[1];
    float*       out   = (float*)d_out;

    // ---- binning workspace layout ----
    const size_t cur_bytes = (size_t)NB * sizeof(unsigned int);       // 1 KB
    const size_t rec_off   = 1024;                                    // aligned
    const size_t rec_bytes = (size_t)NB * CAP * sizeof(unsigned int); // 14.68 MB
    const size_t bin_need  = rec_off + rec_bytes;

    const size_t grad_bytes = (size_t)N_NODES * HDIM * sizeof(__half2); // 6.4 MB
    const size_t f16_need   = grad_bytes + sizeof(float);

    if (ws_size >= bin_need) {
        unsigned int* gcursor = (unsigned int*)d_ws;
        unsigned int* recs_g  = (unsigned int*)((char*)d_ws + rec_off);

        hipMemsetAsync(gcursor, 0, cur_bytes, stream);
        // grad merge uses dense atomics from 2 blocks/bucket -> zero all out
        hipMemsetAsync(out, 0, (size_t)(1 + N_NODES * DIM) * sizeof(float),
                       stream);
        bin_kernel<<<NT, 256, 0, stream>>>(edges, gcursor, recs_g);
        gather_kernel<<<NB * GPB, 1024, 0, stream>>>(x, recs_g, gcursor, out);
    } else if (ws_size >= f16_need) {
        __half2* grad_h    = (__half2*)d_ws;
        float*   energy_ws = (float*)((char*)d_ws + grad_bytes);

        hipMemsetAsync(d_ws, 0, f16_need, stream);
        spring_edge_f16_kernel<<<4096, 256, 0, stream>>>(x, edges, grad_h,
                                                         energy_ws);
        convert_kernel<<<(N_NODES * HDIM + 255) / 256, 256, 0, stream>>>(
            grad_h, energy_ws, out);
    } else {
        hipMemsetAsync(out, 0, (size_t)out_size * sizeof(float), stream);
        spring_edge_kernel<<<4096, 256, 0, stream>>>(x, edges, out);
    }
}

// Round 5
// 399.140 us; speedup vs baseline: 1.8768x; 1.7230x over previous
//
#include <hip/hip_runtime.h>
#include <hip/hip_fp16.h>
#include <math.h>

#define DIM      32
#define HDIM     16                // DIM/2 float2 pairs per row
#define N_NODES  100000
#define N_EDGES  1600000
#define L0       0.1f

// ---- u-binning parameters ----
#define NB2      512               // u-buckets
#define NPB2     196               // nodes per bucket (511*196 >= 100000)
#define NBUCK    511               // buckets actually populated
#define CAP      4032              // records/bucket (mean 3136, +16 sigma)
#define TILE     2048              // edges per bin tile
#define NT       ((N_EDGES + TILE - 1) / TILE)   // 782 tiles

// ===========================================================================
// R4 post-mortem: binned gather was outstanding-miss-bound — only 4 cold rows
// in flight per wave (vs R0's 16), and it doubled row reads (xd re-read per
// record).  R5 keeps what works in each structure:
//   - bin EDGES by u (1 record/edge, half of R4's records)
//   - per-bucket kernel: u-grad in a 25KB LDS slice (dedups HALF the atomic
//     line-touches: 204.8MB -> 102.4MB), v-grad via R0's proven f16-packed
//     unsafeAtomicAdd, xv gathers unrolled 4/quad = 16 cold rows per wave
//     (R0-parity MLP), records read as one uint4 broadcast, no barriers.
//   - math chain token-identical to R0 (same p order, clamp, log1p, f).
// ===========================================================================

// ---- Phase 1: tile-local counting sort of edges by u-bucket ----
__global__ __launch_bounds__(512) void bin_u_kernel(
    const int*    __restrict__ edges,
    unsigned int* __restrict__ gcursor,   // NB2 counters (ws, zeroed)
    unsigned int* __restrict__ recs_g)    // NB2*CAP u32 records (ws)
{
    __shared__ unsigned int   recs[TILE];   // 8 KB
    __shared__ unsigned int   srec[TILE];   // 8 KB
    __shared__ unsigned short rb  [TILE];   // 4 KB
    __shared__ unsigned short srb [TILE];   // 4 KB
    __shared__ unsigned int   hist [NB2];
    __shared__ unsigned int   lscan[NB2];
    __shared__ unsigned int   gbase[NB2];
    __shared__ unsigned int   cnt  [NB2];

    const int t    = threadIdx.x;
    const int base = blockIdx.x * TILE;
    const int nrec = min(TILE, N_EDGES - base);

    hist[t] = 0;
    cnt[t]  = 0;
    __syncthreads();

    #pragma unroll
    for (int i = 0; i < TILE / 512; ++i) {
        const int e = base + i * 512 + t;
        if (e < N_EDGES) {
            const int2 ev = ((const int2*)edges)[e];
            const int bu = ev.x / NPB2;
            const int du = ev.x - bu * NPB2;
            recs[i * 512 + t] = (unsigned)du | ((unsigned)ev.y << 9);
            rb[i * 512 + t]   = (unsigned short)bu;
            atomicAdd(&hist[bu], 1u);
        }
    }
    __syncthreads();

    // inclusive scan over 512 buckets
    lscan[t] = hist[t];
    __syncthreads();
    for (int off = 1; off < NB2; off <<= 1) {
        const unsigned add = (t >= off) ? lscan[t - off] : 0u;
        __syncthreads();
        lscan[t] += add;
        __syncthreads();
    }
    const unsigned myCnt = hist[t];
    gbase[t] = myCnt ? atomicAdd(&gcursor[t], myCnt) : 0u;
    const unsigned excl = lscan[t] - myCnt;
    __syncthreads();
    lscan[t] = excl;
    __syncthreads();

    for (int r = t; r < nrec; r += 512) {
        const unsigned short b  = rb[r];
        const unsigned int   lo = atomicAdd(&cnt[b], 1u);
        const unsigned int   pos = lscan[b] + lo;
        srec[pos] = recs[r];
        srb[pos]  = b;
    }
    __syncthreads();

    for (int j = t; j < nrec; j += 512) {
        const unsigned short b   = srb[j];
        const unsigned int   idx = gbase[b] + ((unsigned)j - lscan[b]);
        if (idx < CAP)                          // defensive (+16 sigma margin)
            recs_g[(unsigned)b * CAP + idx] = srec[j];
    }
}

// ---- Phase 2: one block per u-bucket.  u-grad in LDS slice; v-grad via
//      R0's f16-packed global atomics; 4 records/quad in flight. ----
__global__ __launch_bounds__(1024) void bucket_kernel(
    const float*        __restrict__ x,
    const unsigned int* __restrict__ recs_g,
    const unsigned int* __restrict__ gcursor,
    __half2*            __restrict__ grad_h,  // N_NODES*HDIM (ws, zeroed)
    float*              __restrict__ out)     // out[0] energy (pre-zeroed)
{
    __shared__ float  lg[NPB2 * DIM];         // 25,088 B u-grad slice
    __shared__ double s_e[16];

    const int b     = blockIdx.x;
    const int t     = threadIdx.x;
    const int lane  = t & 63;
    const int k     = lane & 15;              // float2 pair index
    const int qId   = (t >> 6) * 4 + (lane >> 4);   // quad id 0..63
    const int node0 = b * NPB2;
    const int nnode = min(NPB2, N_NODES - node0);

    for (int j = t; j < NPB2 * DIM; j += 1024) lg[j] = 0.0f;
    __syncthreads();

    const int nrec = min((int)gcursor[b], CAP);
    const float2* __restrict__ x2 = (const float2*)x;
    const float Jx = (k == 0) ? -1.0f : 1.0f;
    const int qBase = b * CAP;

    double energy = 0.0;

    for (int i = 4 * qId; i < nrec; i += 256) {
        const int rem = nrec - i;             // >= 1
        uint4 rr;
        if (rem >= 4) {
            rr = *reinterpret_cast<const uint4*>(recs_g + qBase + i);
        } else {
            rr.x = recs_g[qBase + i];
            rr.y = (rem > 1) ? recs_g[qBase + i + 1] : 0u;
            rr.z = (rem > 2) ? recs_g[qBase + i + 2] : 0u;
            rr.w = 0u;
        }
        const int n = min(rem, 4);
        const unsigned int rec[4] = {rr.x, rr.y, rr.z, rr.w};

        int dl[4], v[4];
        float2 xu[4], xv[4];
        #pragma unroll
        for (int r = 0; r < 4; ++r) {
            dl[r] = (int)(rec[r] & 511u);
            v[r]  = (int)(rec[r] >> 9);
            xu[r] = x2[(node0 + dl[r]) * HDIM + k];   // warm (25KB slice)
            xv[r] = x2[v[r] * HDIM + k];              // cold gather
        }

        float p[4];
        #pragma unroll
        for (int r = 0; r < 4; ++r)
            p[r] = Jx * xu[r].x * xv[r].x + xu[r].y * xv[r].y;
        #pragma unroll
        for (int off = 8; off; off >>= 1) {
            #pragma unroll
            for (int r = 0; r < 4; ++r)
                p[r] += __shfl_xor(p[r], off, 16);
        }

        #pragma unroll
        for (int r = 0; r < 4; ++r) {
            if (r < n) {
                const float inner = fminf(p[r], -1.0000001f);
                const float zm1   = -inner - 1.0f;
                const float s     = sqrtf(zm1 * (zm1 + 2.0f));
                const float dist  = log1pf(zm1 + s);
                const float delta = dist - L0;
                const float f     = -delta / (s + 1e-9f);
                // v-side: identical pipe to R0 (f16-packed atomic)
                unsafeAtomicAdd(&grad_h[v[r] * HDIM + k],
                                __floats2half2_rn(f * Jx * xu[r].x,
                                                  f * xu[r].y));
                // u-side: f32 LDS slice (dedup'd, written once at the end)
                atomicAdd(&lg[dl[r] * DIM + 2 * k],     f * Jx * xv[r].x);
                atomicAdd(&lg[dl[r] * DIM + 2 * k + 1], f * xv[r].y);
                if (k == 0)
                    energy += 0.5 * (double)delta * (double)delta;
            }
        }
    }

    // energy reduce: wave butterfly -> block -> one global atomic
    #pragma unroll
    for (int off = 32; off; off >>= 1)
        energy += __shfl_xor(energy, off, 64);
    if (lane == 0) s_e[t >> 6] = energy;
    __syncthreads();                 // also orders LDS atomics before writeout
    if (t == 0) {
        double tot = 0.0;
        #pragma unroll
        for (int w = 0; w < 16; ++w) tot += s_e[w];
        atomicAdd(&out[0], (float)tot);
    }

    // exclusive slice -> plain coalesced stores (no memset, no merge atomics)
    float* __restrict__ grad = out + 1;
    const int lim = nnode * DIM;
    for (int j = t; j < lim; j += 1024)
        grad[node0 * DIM + j] = lg[j];
}

// ---- Phase 3: add the f16 v-side accumulator into out (RMW, exclusive) ----
__global__ __launch_bounds__(256) void combine_kernel(
    const __half2* __restrict__ grad_h,
    float*         __restrict__ out)
{
    const int i = blockIdx.x * 256 + threadIdx.x;     // over N_NODES*HDIM
    if (i < N_NODES * HDIM) {
        const float2 f = __half22float2(grad_h[i]);
        out[1 + 2 * i]     += f.x;
        out[1 + 2 * i + 1] += f.y;
    }
}

// ===========================================================================
// Fallback 1 (ws >= 6.4MB): round-0 f16-packed-atomic kernel, 266 us.
// ===========================================================================
__global__ __launch_bounds__(256) void spring_edge_f16_kernel(
    const float*  __restrict__ x,
    const int*    __restrict__ edges,
    __half2*      __restrict__ grad_h,
    float*        __restrict__ energy_ws)
{
    const int tid   = threadIdx.x;
    const int lane  = tid & 63;
    const int k     = lane & 15;
    const int quad  = lane >> 4;
    const int qId   = ((blockIdx.x * blockDim.x + tid) >> 6) * 4 + quad;
    const int nQuad = ((gridDim.x * blockDim.x) >> 6) * 4;

    const float2* __restrict__ x2 = (const float2*)x;
    const float Jx = (k == 0) ? -1.0f : 1.0f;

    double energy = 0.0;

    for (int e0 = qId; e0 < N_EDGES; e0 += 2 * nQuad) {
        const int  e1 = e0 + nQuad;
        const bool a1 = (e1 < N_EDGES);

        const int2 ev0 = ((const int2*)edges)[e0];
        const int2 ev1 = a1 ? ((const int2*)edges)[e1] : make_int2(0, 0);
        const float2 xu0 = x2[ev0.x * HDIM + k];
        const float2 xv0 = x2[ev0.y * HDIM + k];
        const float2 xu1 = x2[ev1.x * HDIM + k];
        const float2 xv1 = x2[ev1.y * HDIM + k];

        float p0 = Jx * xu0.x * xv0.x + xu0.y * xv0.y;
        float p1 = Jx * xu1.x * xv1.x + xu1.y * xv1.y;
        #pragma unroll
        for (int off = 8; off; off >>= 1) {
            p0 += __shfl_xor(p0, off, 16);
            p1 += __shfl_xor(p1, off, 16);
        }

        {
            const float inner = fminf(p0, -1.0000001f);
            const float zm1   = -inner - 1.0f;
            const float s     = sqrtf(zm1 * (zm1 + 2.0f));
            const float dist  = log1pf(zm1 + s);
            const float delta = dist - L0;
            const float f     = -delta / (s + 1e-9f);
            unsafeAtomicAdd(&grad_h[ev0.x * HDIM + k],
                            __floats2half2_rn(f * Jx * xv0.x, f * xv0.y));
            unsafeAtomicAdd(&grad_h[ev0.y * HDIM + k],
                            __floats2half2_rn(f * Jx * xu0.x, f * xu0.y));
            if (k == 0) energy += 0.5 * (double)delta * (double)delta;
        }
        if (a1) {
            const float inner = fminf(p1, -1.0000001f);
            const float zm1   = -inner - 1.0f;
            const float s     = sqrtf(zm1 * (zm1 + 2.0f));
            const float dist  = log1pf(zm1 + s);
            const float delta = dist - L0;
            const float f     = -delta / (s + 1e-9f);
            unsafeAtomicAdd(&grad_h[ev1.x * HDIM + k],
                            __floats2half2_rn(f * Jx * xv1.x, f * xv1.y));
            unsafeAtomicAdd(&grad_h[ev1.y * HDIM + k],
                            __floats2half2_rn(f * Jx * xu1.x, f * xu1.y));
            if (k == 0) energy += 0.5 * (double)delta * (double)delta;
        }
    }

    #pragma unroll
    for (int off = 32; off; off >>= 1)
        energy += __shfl_xor(energy, off, 64);

    __shared__ double s_e[4];
    if (lane == 0) s_e[tid >> 6] = energy;
    __syncthreads();
    if (tid == 0)
        atomicAdd(energy_ws, (float)(s_e[0] + s_e[1] + s_e[2] + s_e[3]));
}

__global__ __launch_bounds__(256) void convert_kernel(
    const __half2* __restrict__ grad_h,
    const float*   __restrict__ energy_ws,
    float*         __restrict__ out)
{
    const int i = blockIdx.x * 256 + threadIdx.x;
    if (i < N_NODES * HDIM) {
        const float2 f = __half22float2(grad_h[i]);
        out[1 + 2 * i]     = f.x;
        out[1 + 2 * i + 1] = f.y;
    }
    if (i == 0) out[0] = *energy_ws;
}

// ===========================================================================
// Fallback 2 (no usable ws): known-correct fused kernel.
// ===========================================================================
__global__ __launch_bounds__(256) void spring_edge_kernel(
    const float* __restrict__ x,
    const int*   __restrict__ edges,
    float*       __restrict__ out)
{
    const int tid    = threadIdx.x;
    const int lane   = tid & 63;
    const int d      = lane & 31;
    const int half   = lane >> 5;
    const int waveId = (blockIdx.x * blockDim.x + tid) >> 6;
    const int nWaves = (gridDim.x * blockDim.x) >> 6;

    float* __restrict__ grad = out + 1;
    const float Jd = (d == 0) ? -1.0f : 1.0f;
    double energy = 0.0;

    for (int e0 = waveId * 2; e0 < N_EDGES; e0 += nWaves * 2) {
        const int  e      = e0 + half;
        const bool active = (e < N_EDGES);
        int u = 0, v = 0;
        float xu = 0.0f, xv = 0.0f;
        if (active) {
            u  = edges[2 * e];
            v  = edges[2 * e + 1];
            xu = x[u * DIM + d];
            xv = x[v * DIM + d];
        }
        float p = xu * xv;
        if (d == 0) p = -p;
        #pragma unroll
        for (int off = 16; off; off >>= 1)
            p += __shfl_xor(p, off, 32);

        const float inner  = fminf(p, -1.0000001f);
        const float zm1    = -inner - 1.0f;
        const float s      = sqrtf(zm1 * (zm1 + 2.0f));
        const float dist   = log1pf(zm1 + s);
        const float delta  = dist - L0;
        const float factor = -delta / (s + 1e-9f);

        if (active) {
            atomicAdd(&grad[u * DIM + d], factor * xv * Jd);
            atomicAdd(&grad[v * DIM + d], factor * xu * Jd);
            if (d == 0)
                energy += 0.5 * (double)delta * (double)delta;
        }
    }
    #pragma unroll
    for (int off = 32; off; off >>= 1)
        energy += __shfl_xor(energy, off, 64);
    __shared__ double s_e[4];
    if (lane == 0) s_e[tid >> 6] = energy;
    __syncthreads();
    if (tid == 0)
        atomicAdd(&out[0], (float)(s_e[0] + s_e[1] + s_e[2] + s_e[3]));
}

extern "C" void kernel_launch(void* const* d_in, const int* in_sizes, int n_in,
                              void* d_out, int out_size, void* d_ws, size_t ws_size,
                              hipStream_t stream) {
    const float* x     = (const float*)d_in[0];
    const int*   edges = (const int*)d_in[1];
    float*       out   = (float*)d_out;

    // ---- u-binned workspace layout ----
    const size_t cur_bytes = (size_t)NB2 * sizeof(unsigned int);        // 2 KB
    const size_t rec_off   = 4096;
    const size_t rec_bytes = (size_t)NB2 * CAP * sizeof(unsigned int);  // 8.26 MB
    const size_t gh_off    = rec_off + rec_bytes;
    const size_t gh_bytes  = (size_t)N_NODES * HDIM * sizeof(__half2);  // 6.4 MB
    const size_t ubin_need = gh_off + gh_bytes;                         // 14.66 MB

    const size_t f16_need  = gh_bytes + sizeof(float);

    if (ws_size >= ubin_need) {
        unsigned int* gcursor = (unsigned int*)d_ws;
        unsigned int* recs_g  = (unsigned int*)((char*)d_ws + rec_off);
        __half2*      grad_h  = (__half2*)((char*)d_ws + gh_off);

        hipMemsetAsync(gcursor, 0, cur_bytes, stream);
        hipMemsetAsync(grad_h, 0, gh_bytes, stream);
        hipMemsetAsync(out, 0, sizeof(float), stream);    // energy slot only
        bin_u_kernel<<<NT, 512, 0, stream>>>(edges, gcursor, recs_g);
        bucket_kernel<<<NBUCK, 1024, 0, stream>>>(x, recs_g, gcursor,
                                                  grad_h, out);
        combine_kernel<<<(N_NODES * HDIM + 255) / 256, 256, 0, stream>>>(
            grad_h, out);
    } else if (ws_size >= f16_need) {
        __half2* grad_h    = (__half2*)d_ws;
        float*   energy_ws = (float*)((char*)d_ws + gh_bytes);

        hipMemsetAsync(d_ws, 0, f16_need, stream);
        spring_edge_f16_kernel<<<4096, 256, 0, stream>>>(x, edges, grad_h,
                                                         energy_ws);
        convert_kernel<<<(N_NODES * HDIM + 255) / 256, 256, 0, stream>>>(
            grad_h, energy_ws, out);
    } else {
        hipMemsetAsync(out, 0, (size_t)out_size * sizeof(float), stream);
        spring_edge_kernel<<<4096, 256, 0, stream>>>(x, edges, out);
    }
}